// Round 5
// baseline (506.002 us; speedup 1.0000x reference)
//
#include <hip/hip_runtime.h>
#include <hip/hip_bf16.h>

// CoincidenceDetector: S[b,n] = sum_d |w_d| * [|q-pt|<5] * exp(-|q-pt|/3)
// pt = 20 - 15*sigmoid(patterns)
//
// R5 = R3 design, de-risked resubmit (two infra failures; no measurement yet).
// 1-wave blocks, (64n x 64d x 16b) per block:
//  - Ep0/Ip0 = e^{+-pt/3} (w-free) in 128 VGPRs (per-lane, lane<->n)
//  - Eq/Iq   = e^{+-q/3} in LDS, uniform ds_read_b128 broadcasts
//  - |w| pinned to SGPRs (readfirstlane); window test vs literal theta
//    (w-free: min(a0,b0) > e^{-5/3} <=> |dt| < 5); weight applied by fmac.
//  - inner loop: mul,mul,min,cmp-lit,cndmask,fmac = 6 VALU/elem, no memory
//    ops except uniform LDS broadcasts. No s_load waits in steady state.
// Partials over 4 d-slices -> d_ws (R2 counters prove ws >= 16.8 MB), then
// cd_reduce folds them into d_out.

static constexpr float kC2    = 0.48089834696298783f;   // 1/(3*ln2)
static constexpr float kL2E   = 1.4426950408889634f;    // log2(e)
static constexpr float kTheta = 0.18887560283756183f;   // exp(-5/3)

#define B_  64
#define N_  16384
#define D_  256
#define NT  64          // n per block (= lanes)
#define DT  64          // d per block
#define BT  16          // b per block
#define DSL (D_ / DT)   // 4 d-slices -> partials

__global__ __launch_bounds__(64, 3) void cd_main(
        const float* __restrict__ q,
        const float* __restrict__ patterns,
        const float* __restrict__ weights,
        float* __restrict__ outp)
{
    __shared__ float sEq[BT * DT];   // 4 KB
    __shared__ float sIq[BT * DT];   // 4 KB

    const int l   = threadIdx.x;     // 0..63, lane = local n
    const int bid = blockIdx.x;      // = bq*1024 + dq*256 + nt
    const int nt  = bid & 255;
    const int dq  = (bid >> 8) & (DSL - 1);
    const int bq  = bid >> 10;
    const int n0  = nt * NT, d0 = dq * DT, b0 = bq * BT;

    // ---- stage Eq/Iq for 16 b x 64 d into LDS (coalesced q rows)
    for (int r = 0; r < BT; ++r) {
        float qv = q[(size_t)(b0 + r) * D_ + d0 + l];
        float u  = qv * kC2;
        sEq[r * DT + l] = exp2f(u);
        sIq[r * DT + l] = exp2f(-u);
    }

    // ---- |w| pinned to SGPRs (uniform loads, forced scalar)
    float wS[DT];
#pragma unroll
    for (int i = 0; i < DT; ++i) {
        float wa = fabsf(weights[d0 + i]);
        wS[i] = __int_as_float(__builtin_amdgcn_readfirstlane(__float_as_int(wa)));
    }

    // ---- per-lane Ep0/Ip0 (w-free) for n = n0 + l, 64 d in VGPRs
    float ep[DT], ip[DT];
    const float4* pat4 = (const float4*)(patterns + (size_t)(n0 + l) * D_ + d0);
#pragma unroll
    for (int i = 0; i < DT / 4; ++i) {
        float4 x4 = pat4[i];
        float xs[4] = {x4.x, x4.y, x4.z, x4.w};
#pragma unroll
        for (int j = 0; j < 4; ++j) {
            float t  = exp2f(-xs[j] * kL2E);               // e^{-x}
            float sg = 1.0f / (1.0f + t);                  // sigmoid
            float u  = fmaf(-15.0f * kC2, sg, 20.0f * kC2);// pt/(3 ln2)
            ep[i * 4 + j] = exp2f(u);
            ip[i * 4 + j] = exp2f(-u);
        }
    }

    __syncthreads();

    // ---- hot loop: 16 b x 64 d, 6 VALU per element
#pragma unroll 2
    for (int b = 0; b < BT; ++b) {
        const float4* eq4 = (const float4*)&sEq[b * DT];
        const float4* iq4 = (const float4*)&sIq[b * DT];
        float acc = 0.0f;
#pragma unroll
        for (int g = 0; g < DT / 4; ++g) {
            float4 eq = eq4[g];                  // uniform ds_read_b128
            float4 iq = iq4[g];
            float equ[4] = {eq.x, eq.y, eq.z, eq.w};
            float iqu[4] = {iq.x, iq.y, iq.z, iq.w};
#pragma unroll
            for (int j = 0; j < 4; ++j) {
                int d = g * 4 + j;
                float a = equ[j] * ip[d];        // v_mul
                float c = iqu[j] * ep[d];        // v_mul
                float k = fminf(a, c);           // v_min
                float m = (k > kTheta) ? k : 0.0f; // v_cmp(lit) + v_cndmask
                acc = fmaf(m, wS[d], acc);       // v_fmac (SGPR weight)
            }
        }
        // partials: [dq][b][n]
        outp[((size_t)dq * B_ + (b0 + b)) * N_ + n0 + l] = acc;
    }
}

__global__ void cd_reduce(const float4* __restrict__ part, float4* __restrict__ S) {
    const int PQ = B_ * N_ / 4;                   // float4s per slice
    int i = blockIdx.x * 256 + threadIdx.x;
    float4 a = part[i];
    float4 b = part[i + PQ];
    float4 c = part[i + 2 * PQ];
    float4 d = part[i + 3 * PQ];
    float4 r;
    r.x = (a.x + b.x) + (c.x + d.x);
    r.y = (a.y + b.y) + (c.y + d.y);
    r.z = (a.z + b.z) + (c.z + d.z);
    r.w = (a.w + b.w) + (c.w + d.w);
    S[i] = r;
}

extern "C" void kernel_launch(void* const* d_in, const int* in_sizes, int n_in,
                              void* d_out, int out_size, void* d_ws, size_t ws_size,
                              hipStream_t stream) {
    const float* q        = (const float*)d_in[0];
    const float* patterns = (const float*)d_in[1];
    const float* weights  = (const float*)d_in[2];
    float* S    = (float*)d_out;
    float* part = (float*)d_ws;                   // DSL * B * N floats = 16.8 MB

    const int grid = (N_ / NT) * DSL * (B_ / BT); // 4096
    cd_main<<<grid, NT, 0, stream>>>(q, patterns, weights, part);
    cd_reduce<<<(B_ * N_ / 4) / 256, 256, 0, stream>>>((const float4*)part, (float4*)S);
}

// Round 6
// 125.152 us; speedup vs baseline: 4.0431x; 4.0431x over previous
//
#include <hip/hip_runtime.h>
#include <hip/hip_bf16.h>

// CoincidenceDetector: S[b,n] = sum_d |w_d| * [|q-pt|<5] * exp(-|q-pt|/3)
// pt = 20 - 15*sigmoid(patterns)
//
// exp(-|dt|/3) = min(Eq*Ip, Iq*Ep); |w| folded into pattern side (w>=0 =>
// w*min(a,c) = min(w*a, w*c)); window |dt|<5 <=> k' > theta*|w| (strict).
// Inner: mul, mul, min, cmp, cndmask, add = 6 full-rate VALU / element.
//
// R6 vs R5 (506us, 1.06GB scratch traffic, VGPR=84): R5's 64-deep per-lane
// arrays (wS/ep/ip) were demoted to scratch -> per-element scratch reads.
// Fix: ALL per-lane arrays <=16 elements, statically indexed; d chunked by 8;
// pattern-side regs live only within a chunk. Eq/Iq via uniform ds_read_b128
// broadcasts (8KB LDS). No SGPR pinning, no scalar loads in hot loop.

static constexpr float kC2    = 0.48089834696298783f;   // 1/(3*ln2)
static constexpr float kL2E   = 1.4426950408889634f;    // log2(e)
static constexpr float kTheta = 0.18887560283756183f;   // exp(-5/3)

#define B_   64
#define N_   16384
#define D_   256
#define NT   64     // n per block (= lanes)
#define BT   16     // b per block
#define DSL  4      // d-slices (partials in ws)
#define DS_  64     // d per slice
#define DC   8      // d per chunk

__global__ __launch_bounds__(64, 4) void cd_main(
        const float* __restrict__ q,
        const float* __restrict__ patterns,
        const float* __restrict__ weights,
        float* __restrict__ outp)
{
    __shared__ float sEq[BT * DS_];   // 4 KB
    __shared__ float sIq[BT * DS_];   // 4 KB

    const int l   = threadIdx.x;              // lane = local n
    const int bid = blockIdx.x;               // nt + dq*256 + bq*1024
    const int nt  = bid & 255;
    const int dq  = (bid >> 8) & (DSL - 1);
    const int bq  = bid >> 10;
    const int n0  = nt * NT, d0 = dq * DS_, b0 = bq * BT;

    // ---- stage Eq/Iq tile (16 b x 64 d), coalesced, once per block
#pragma unroll 4
    for (int r = 0; r < BT; ++r) {
        float qv = q[(size_t)(b0 + r) * D_ + d0 + l];
        float u  = qv * kC2;
        sEq[r * DS_ + l] = exp2f(u);
        sIq[r * DS_ + l] = exp2f(-u);
    }
    __syncthreads();

    float acc[BT];
#pragma unroll
    for (int i = 0; i < BT; ++i) acc[i] = 0.0f;

    const float* prow = patterns + (size_t)(n0 + l) * D_ + d0;

    for (int dc = 0; dc < DS_ / DC; ++dc) {   // 8 chunks, rolled (I$-friendly)
        // ---- per-lane pattern staging for this 8-d chunk (24 live regs)
        float4 x0 = *(const float4*)(prow + dc * DC);
        float4 x1 = *(const float4*)(prow + dc * DC + 4);
        float4 w0 = *(const float4*)(weights + d0 + dc * DC);
        float4 w1 = *(const float4*)(weights + d0 + dc * DC + 4);
        float xs[8] = {x0.x, x0.y, x0.z, x0.w, x1.x, x1.y, x1.z, x1.w};
        float wv[8] = {w0.x, w0.y, w0.z, w0.w, w1.x, w1.y, w1.z, w1.w};
        float ep[8], ip[8], tw[8];
#pragma unroll
        for (int j = 0; j < 8; ++j) {
            float t  = exp2f(-xs[j] * kL2E);              // e^{-x}
            float sg = __fdividef(1.0f, 1.0f + t);        // sigmoid (fast rcp)
            float u  = fmaf(-15.0f * kC2, sg, 20.0f * kC2); // pt/(3 ln2)
            float wa = fabsf(wv[j]);
            ep[j] = wa * exp2f(u);
            ip[j] = wa * exp2f(-u);
            tw[j] = kTheta * wa;
        }
        // ---- 16 b x 8 d: uniform LDS broadcasts + 6 VALU/elem
#pragma unroll
        for (int b = 0; b < BT; ++b) {
            const float* eqb = &sEq[b * DS_ + dc * DC];
            const float* iqb = &sIq[b * DS_ + dc * DC];
            float4 ea = *(const float4*)eqb;
            float4 eb = *(const float4*)(eqb + 4);
            float4 ia = *(const float4*)iqb;
            float4 ib = *(const float4*)(iqb + 4);
            float eu[8] = {ea.x, ea.y, ea.z, ea.w, eb.x, eb.y, eb.z, eb.w};
            float iu[8] = {ia.x, ia.y, ia.z, ia.w, ib.x, ib.y, ib.z, ib.w};
            float m[8];
#pragma unroll
            for (int j = 0; j < 8; ++j) {
                float a = eu[j] * ip[j];          // v_mul
                float c = iu[j] * ep[j];          // v_mul
                float k = fminf(a, c);            // v_min
                m[j] = (k > tw[j]) ? k : 0.0f;    // v_cmp + v_cndmask
            }
            acc[b] += ((m[0] + m[1]) + (m[2] + m[3]))
                    + ((m[4] + m[5]) + (m[6] + m[7]));   // 8 adds, depth 3
        }
    }

    // partials: [dq][b][n], coalesced per b
#pragma unroll
    for (int b = 0; b < BT; ++b)
        outp[((size_t)dq * B_ + (b0 + b)) * N_ + n0 + l] = acc[b];
}

__global__ void cd_reduce(const float4* __restrict__ part, float4* __restrict__ S) {
    const int PQ = B_ * N_ / 4;                   // float4s per slice
    int i = blockIdx.x * 256 + threadIdx.x;
    float4 a = part[i];
    float4 b = part[i + PQ];
    float4 c = part[i + 2 * PQ];
    float4 d = part[i + 3 * PQ];
    float4 r;
    r.x = (a.x + b.x) + (c.x + d.x);
    r.y = (a.y + b.y) + (c.y + d.y);
    r.z = (a.z + b.z) + (c.z + d.z);
    r.w = (a.w + b.w) + (c.w + d.w);
    S[i] = r;
}

extern "C" void kernel_launch(void* const* d_in, const int* in_sizes, int n_in,
                              void* d_out, int out_size, void* d_ws, size_t ws_size,
                              hipStream_t stream) {
    const float* q        = (const float*)d_in[0];
    const float* patterns = (const float*)d_in[1];
    const float* weights  = (const float*)d_in[2];
    float* S    = (float*)d_out;
    float* part = (float*)d_ws;                   // DSL * B * N floats = 16.8 MB

    const int grid = 256 * DSL * (B_ / BT);       // 4096 one-wave blocks
    cd_main<<<grid, NT, 0, stream>>>(q, patterns, weights, part);
    cd_reduce<<<(B_ * N_ / 4) / 256, 256, 0, stream>>>((const float4*)part, (float4*)S);
}